// Round 10
// baseline (91.500 us; speedup 1.0000x reference)
//
#include <hip/hip_runtime.h>

// SAGEEncode fused: B=2048, F1=10, F2=25, D=128, H=256, N=261
// R10 = R7 template with streaming occupancy raised 2.5x:
//   ITEMS=2, THREADS=320 (5 waves), grid 1024 -> 4 blocks/CU = 20 waves/CU.
//   NO launch_bounds min-waves clamp (R5/R6's 128-VGPR clamp likely spilled).
//   Phase1 = R7's group-per-pair mapping: 10 groups x 2 pairs, balanced,
//   full-unroll j-loop. Wave 4 streams but exec-masks out of GEMM phases
//   (reaches all barriers). GEMM/epilogue byte-equivalent to R7 at ITEMS=2.
// K0 prep_weights: W1,W2 f32 -> W1t[256][256], W2t[256][512] bf16. 96 blocks.

#define NB 2048
#define F1 10
#define F2 25
#define DD 128
#define HH 256
#define NN 261
#define ITEMS 2
#define THREADS 320

typedef __attribute__((ext_vector_type(8))) short short8;   // 8 bf16
typedef __attribute__((ext_vector_type(4))) float f32x4;    // MFMA acc

__device__ __forceinline__ ushort f2bf(float f) {           // RNE, finite
    unsigned u = __builtin_bit_cast(unsigned, f);
    u = (u + 0x7FFFu + ((u >> 16) & 1u)) >> 16;
    return (ushort)u;
}
__device__ __forceinline__ float bf2f(ushort h) {
    unsigned u = ((unsigned)h) << 16;
    return __builtin_bit_cast(float, u);
}
// XOR-swizzle on ushort index (byte bits 4..6): A-frag ds_read_b128 lands
// exactly 8 dwords/bank (minimum). Flips ushort bits 3..5 -> preserves
// 8B (ushort4) alignment.
__device__ __forceinline__ int swz(int uidx, int row) {
    return uidx ^ ((row & 7) << 3);
}

// ---------------- K0: weight transpose+convert (96 blocks) ----------------
__global__ __launch_bounds__(256)
void prep_weights(const float* __restrict__ W1, const float* __restrict__ W2,
                  ushort* __restrict__ W1t, ushort* __restrict__ W2t)
{
    __shared__ float tile[32][65];
    const int b = blockIdx.x, t = threadIdx.x;
    const float* src; ushort* dst; int K, c0, k0;
    if (b < 32) { src = W1; dst = W1t; K = 2 * DD;
                  c0 = (b & 7) * 32; k0 = (b >> 3) * 64; }
    else { int bb = b - 32; src = W2; dst = W2t; K = 2 * HH;
           c0 = (bb & 7) * 32; k0 = (bb >> 3) * 64; }

    #pragma unroll
    for (int kr = 0; kr < 8; ++kr) {
        int kl = kr * 8 + (t >> 5);
        tile[t & 31][kl] = src[(size_t)(k0 + kl) * HH + c0 + (t & 31)];
    }
    __syncthreads();
    const int cl = t >> 3, kc = t & 7;
    short8 v;
    #pragma unroll
    for (int i = 0; i < 8; ++i) v[i] = (short)f2bf(tile[cl][kc * 8 + i]);
    *reinterpret_cast<short8*>(dst + (size_t)(c0 + cl) * K + k0 + kc * 8) = v;
}

// ---------------- K1: fused stream + MFMA ----------------
__global__ __launch_bounds__(THREADS)
void sage_fused(const float* __restrict__ x, const ushort* __restrict__ W1t,
                const ushort* __restrict__ W2t, const float* __restrict__ b1,
                const float* __restrict__ b2, float* __restrict__ out)
{
    __shared__ ushort featL[ITEMS * 16 * 256];   // 16 KB, swizzled rows
    __shared__ ushort f2lds[16][520];            // 16.6 KB (rows>=ITEMS zero)

    const int t = threadIdx.x;
    const int w = t >> 6, l = t & 63;
    const int item0 = blockIdx.x * ITEMS;
    const size_t base = (size_t)item0 * (NN * DD);

    // ---- Phase 1: 10 groups of 32 lanes; group g does (item=p, f=g), p=0,1.
    //      26 x 16B loads per lane per pair, full unroll (R7-proven).
    {
        const int g = t >> 5, d4 = t & 31;       // g: 0..9
        #pragma unroll
        for (int p = 0; p < 2; ++p) {
            const int item = p, f = g;
            const float4* xb = reinterpret_cast<const float4*>(x + base + (size_t)item * (NN * DD));
            float4 h1 = xb[(1 + f) * 32 + d4];
            float4 s = make_float4(0.f, 0.f, 0.f, 0.f);
            const float4* h2 = xb + (1 + F1 + f * F2) * 32 + d4;
            #pragma unroll
            for (int j = 0; j < F2; ++j) {       // full unroll: 25 loads in flight
                float4 v = h2[j * 32];
                s.x += v.x; s.y += v.y; s.z += v.z; s.w += v.w;
            }
            const float invF2 = 1.f / F2;
            int row = 1 + f;
            int ub = (item * 16 + row) * 256;
            ushort4 lo = { f2bf(h1.x), f2bf(h1.y), f2bf(h1.z), f2bf(h1.w) };
            ushort4 hi = { f2bf(s.x * invF2), f2bf(s.y * invF2),
                           f2bf(s.z * invF2), f2bf(s.w * invF2) };
            *reinterpret_cast<ushort4*>(&featL[swz(ub + d4 * 4, row)]) = lo;
            *reinterpret_cast<ushort4*>(&featL[swz(ub + DD + d4 * 4, row)]) = hi;
        }
    }
    __syncthreads();

    // ---- Phase 1b: row0 = [seeds | mean(hop1 from LDS bf16)] + zero pads
    if (t < 256) {
        int item = t >> 7, d = t & 127;          // 2 items x 128 dims
        int r0 = item * 16 * 256;
        float sv = x[base + (size_t)item * (NN * DD) + d];
        featL[swz(r0 + d, 0)] = f2bf(sv);
        float m = 0.f;
        #pragma unroll
        for (int f = 1; f <= F1; ++f) m += bf2f(featL[swz(r0 + f * 256 + d, f)]);
        featL[swz(r0 + DD + d, 0)] = f2bf(m * (1.f / F1));
    }
    {
        short8 zz = { 0, 0, 0, 0, 0, 0, 0, 0 };
        for (int z = t; z < ITEMS * 5 * 32; z += THREADS) {   // feat rows 11..15
            int item = z / 160, rem = z % 160;
            int row = 11 + rem / 32, kc = rem % 32;
            *reinterpret_cast<short8*>(&featL[swz((item * 16 + row) * 256 + kc * 8, row)]) = zz;
        }
        for (int z = t; z < (16 - ITEMS) * 64; z += THREADS) { // f2 rows 2..15
            int row = ITEMS + (z >> 6), kc = z & 63;
            *reinterpret_cast<short8*>(&f2lds[row][kc * 8]) = zz;
        }
    }
    __syncthreads();

    // ---- GEMM1: h(32x256) = relu(feat @ W1 + b1); waves 0..3, wave 4 idles
    const int lr = l & 15, lg = l >> 4;
    if (w < 4) {
        f32x4 acc[ITEMS][4];
        #pragma unroll
        for (int it = 0; it < ITEMS; ++it)
            #pragma unroll
            for (int i = 0; i < 4; ++i) acc[it][i] = (f32x4){0.f, 0.f, 0.f, 0.f};

        #pragma unroll 2
        for (int kt = 0; kt < 8; ++kt) {
            short8 af[ITEMS], bf[4];
            #pragma unroll
            for (int it = 0; it < ITEMS; ++it)
                af[it] = *reinterpret_cast<const short8*>(
                    &featL[swz((it * 16 + lr) * 256 + kt * 32 + lg * 8, lr)]);
            #pragma unroll
            for (int i = 0; i < 4; ++i) {
                int col = (w * 4 + i) * 16 + lr;
                bf[i] = *reinterpret_cast<const short8*>(W1t + (size_t)col * 256 + kt * 32 + lg * 8);
            }
            #pragma unroll
            for (int it = 0; it < ITEMS; ++it)
                #pragma unroll
                for (int i = 0; i < 4; ++i)
                    acc[it][i] = __builtin_amdgcn_mfma_f32_16x16x32_bf16(af[it], bf[i], acc[it][i], 0, 0, 0);
        }

        // epilogue: C/D row = lg*4+reg, col = lr. h0 + mean(relu h1 rows 1..10)
        #pragma unroll
        for (int i = 0; i < 4; ++i) {
            const int col = (w * 4 + i) * 16 + lr;
            const float bb = b1[col];
            #pragma unroll
            for (int it = 0; it < ITEMS; ++it) {
                f32x4 a = acc[it][i];
                float r0v = fmaxf(a[0] + bb, 0.f);
                float r1v = fmaxf(a[1] + bb, 0.f);
                float r2v = fmaxf(a[2] + bb, 0.f);
                float r3v = fmaxf(a[3] + bb, 0.f);
                const int rb = lg * 4;
                float p = 0.f;
                p += (rb + 0 >= 1 && rb + 0 <= 10) ? r0v : 0.f;
                p += (rb + 1 >= 1 && rb + 1 <= 10) ? r1v : 0.f;
                p += (rb + 2 >= 1 && rb + 2 <= 10) ? r2v : 0.f;
                p += (rb + 3 >= 1 && rb + 3 <= 10) ? r3v : 0.f;
                p += __shfl_xor(p, 16, 64);
                p += __shfl_xor(p, 32, 64);
                if (lg == 0) {
                    f2lds[it][col]       = f2bf(r0v);
                    f2lds[it][256 + col] = f2bf(p * (1.f / F1));
                }
            }
        }
    }
    __syncthreads();

    // ---- GEMM2: out(2x256) = feat2(2x512) @ W2 + b2; waves 0..3
    if (w < 4) {
        f32x4 acc2[4];
        #pragma unroll
        for (int i = 0; i < 4; ++i) acc2[i] = (f32x4){0.f, 0.f, 0.f, 0.f};
        #pragma unroll 2
        for (int kt = 0; kt < 16; ++kt) {
            short8 a2 = *reinterpret_cast<const short8*>(&f2lds[lr][kt * 32 + lg * 8]);
            #pragma unroll
            for (int i = 0; i < 4; ++i) {
                int col = (w * 4 + i) * 16 + lr;
                short8 bv = *reinterpret_cast<const short8*>(W2t + (size_t)col * 512 + kt * 32 + lg * 8);
                acc2[i] = __builtin_amdgcn_mfma_f32_16x16x32_bf16(a2, bv, acc2[i], 0, 0, 0);
            }
        }
        #pragma unroll
        for (int i = 0; i < 4; ++i) {
            const int col = (w * 4 + i) * 16 + lr;
            const float bb = b2[col];
            #pragma unroll
            for (int r = 0; r < 4; ++r) {
                const int row = lg * 4 + r;
                if (row < ITEMS)
                    out[(size_t)(item0 + row) * HH + col] = acc2[i][r] + bb;
            }
        }
    }
}

extern "C" void kernel_launch(void* const* d_in, const int* in_sizes, int n_in,
                              void* d_out, int out_size, void* d_ws, size_t ws_size,
                              hipStream_t stream) {
    const float* x  = (const float*)d_in[0];
    const float* W1 = (const float*)d_in[1];
    const float* b1 = (const float*)d_in[2];
    const float* W2 = (const float*)d_in[3];
    const float* b2 = (const float*)d_in[4];
    float* out = (float*)d_out;

    ushort* W1t = (ushort*)d_ws;                 // 256*256 bf16 = 128 KB
    ushort* W2t = W1t + 256 * 256;               // 256*512 bf16 = 256 KB

    prep_weights<<<dim3(96), dim3(256), 0, stream>>>(W1, W2, W1t, W2t);
    sage_fused<<<dim3(NB / ITEMS), dim3(THREADS), 0, stream>>>(x, W1t, W2t, b1, b2, out);
}

// Round 12
// 67.805 us; speedup vs baseline: 1.3495x; 1.3495x over previous
//
#include <hip/hip_runtime.h>

// SAGEEncode: B=2048, F1=10, F2=25, D=128, H=256, N=261
// R12 = R7 fused template (race-proven) minus GEMM2, which moves to its own
//   kernel to cut W2 fabric traffic 128 MB -> 32 MB:
//   K0 prep_weights: W1,W2 f32 -> W1t[256][256], W2t[256][512] bf16. 96 blocks.
//   K1 sage_feat:  R7 verbatim through the GEMM1 epilogue; feat2 rows written
//                  bf16 to ws (pure deletions after that — no new sync).
//   K2 sage_gemm2: out(2048x256) = feat2(2048x512) @ W2t + b2. grid 128,
//                  M=16/block, no LDS, B-frags L2-resident (R2-proven shape).

#define NB 2048
#define F1 10
#define F2 25
#define DD 128
#define HH 256
#define NN 261
#define ITEMS 4
#define THREADS 256

typedef __attribute__((ext_vector_type(8))) short short8;   // 8 bf16
typedef __attribute__((ext_vector_type(4))) float f32x4;    // MFMA acc

__device__ __forceinline__ ushort f2bf(float f) {           // RNE, finite
    unsigned u = __builtin_bit_cast(unsigned, f);
    u = (u + 0x7FFFu + ((u >> 16) & 1u)) >> 16;
    return (ushort)u;
}
__device__ __forceinline__ float bf2f(ushort h) {
    unsigned u = ((unsigned)h) << 16;
    return __builtin_bit_cast(float, u);
}
// XOR-swizzle on ushort index (byte bits 4..6): A-frag ds_read_b128 lands
// exactly 8 dwords/bank (minimum). Flips ushort bits 3..5 -> preserves
// 8B (ushort4) alignment.
__device__ __forceinline__ int swz(int uidx, int row) {
    return uidx ^ ((row & 7) << 3);
}

// ---------------- K0: weight transpose+convert (96 blocks) ----------------
__global__ __launch_bounds__(256)
void prep_weights(const float* __restrict__ W1, const float* __restrict__ W2,
                  ushort* __restrict__ W1t, ushort* __restrict__ W2t)
{
    __shared__ float tile[32][65];
    const int b = blockIdx.x, t = threadIdx.x;
    const float* src; ushort* dst; int K, c0, k0;
    if (b < 32) { src = W1; dst = W1t; K = 2 * DD;
                  c0 = (b & 7) * 32; k0 = (b >> 3) * 64; }
    else { int bb = b - 32; src = W2; dst = W2t; K = 2 * HH;
           c0 = (bb & 7) * 32; k0 = (bb >> 3) * 64; }

    #pragma unroll
    for (int kr = 0; kr < 8; ++kr) {
        int kl = kr * 8 + (t >> 5);
        tile[t & 31][kl] = src[(size_t)(k0 + kl) * HH + c0 + (t & 31)];
    }
    __syncthreads();
    const int cl = t >> 3, kc = t & 7;
    short8 v;
    #pragma unroll
    for (int i = 0; i < 8; ++i) v[i] = (short)f2bf(tile[cl][kc * 8 + i]);
    *reinterpret_cast<short8*>(dst + (size_t)(c0 + cl) * K + k0 + kc * 8) = v;
}

// ---------------- K1: fused stream + GEMM1 (R7 template) ----------------
__global__ __launch_bounds__(THREADS)
void sage_feat(const float* __restrict__ x, const ushort* __restrict__ W1t,
               const float* __restrict__ b1, ushort* __restrict__ f2g)
{
    __shared__ ushort featL[ITEMS * 16 * 256];   // 32 KB, swizzled rows

    const int t = threadIdx.x;
    const int item0 = blockIdx.x * ITEMS;
    const size_t base = (size_t)item0 * (NN * DD);

    // ---- Phase 1: stream x -> feat rows 1..10 = [hop1[f] | mean_j hop2[f,j]]
    {
        const int g = t >> 5, d4 = t & 31;
        #pragma unroll
        for (int p = 0; p < 5; ++p) {
            int pi = g + p * 8;                  // 0..39 = item*10 + f
            int item = pi / 10, f = pi % 10;
            const float4* xb = reinterpret_cast<const float4*>(x + base + (size_t)item * (NN * DD));
            float4 h1 = xb[(1 + f) * 32 + d4];
            float4 s = make_float4(0.f, 0.f, 0.f, 0.f);
            const float4* h2 = xb + (1 + F1 + f * F2) * 32 + d4;
            #pragma unroll
            for (int j = 0; j < F2; ++j) {       // full unroll: 25 loads in flight
                float4 v = h2[j * 32];
                s.x += v.x; s.y += v.y; s.z += v.z; s.w += v.w;
            }
            const float invF2 = 1.f / F2;
            int row = 1 + f;
            int ub = (item * 16 + row) * 256;
            ushort4 lo = { f2bf(h1.x), f2bf(h1.y), f2bf(h1.z), f2bf(h1.w) };
            ushort4 hi = { f2bf(s.x * invF2), f2bf(s.y * invF2),
                           f2bf(s.z * invF2), f2bf(s.w * invF2) };
            *reinterpret_cast<ushort4*>(&featL[swz(ub + d4 * 4, row)]) = lo;
            *reinterpret_cast<ushort4*>(&featL[swz(ub + DD + d4 * 4, row)]) = hi;
        }
    }
    __syncthreads();

    // ---- Phase 1b: row0 = [seeds | mean(hop1 from LDS bf16)] + zero pad
    #pragma unroll
    for (int q = 0; q < 2; ++q) {
        int idx = t + q * 256;                   // 0..511
        int item = idx >> 7, d = idx & 127;
        int r0 = item * 16 * 256;
        float sv = x[base + (size_t)item * (NN * DD) + d];
        featL[swz(r0 + d, 0)] = f2bf(sv);
        float m = 0.f;
        #pragma unroll
        for (int f = 1; f <= F1; ++f) m += bf2f(featL[swz(r0 + f * 256 + d, f)]);
        featL[swz(r0 + DD + d, 0)] = f2bf(m * (1.f / F1));
    }
    {
        short8 zz = { 0, 0, 0, 0, 0, 0, 0, 0 };
        for (int z = t; z < ITEMS * 5 * 32; z += THREADS) {   // rows 11..15
            int item = z / 160, rem = z % 160;
            int row = 11 + rem / 32, kc = rem % 32;
            *reinterpret_cast<short8*>(&featL[swz((item * 16 + row) * 256 + kc * 8, row)]) = zz;
        }
    }
    __syncthreads();

    // ---- GEMM1: h(64x256) = relu(feat(64x256) @ W1 + b1), per-item 16-row Mtiles
    const int w = t >> 6, l = t & 63;
    const int lr = l & 15, lg = l >> 4;
    f32x4 acc[ITEMS][4];
    #pragma unroll
    for (int it = 0; it < ITEMS; ++it)
        #pragma unroll
        for (int i = 0; i < 4; ++i) acc[it][i] = (f32x4){0.f, 0.f, 0.f, 0.f};

    #pragma unroll 2
    for (int kt = 0; kt < 8; ++kt) {
        short8 af[ITEMS], bf[4];
        #pragma unroll
        for (int it = 0; it < ITEMS; ++it)
            af[it] = *reinterpret_cast<const short8*>(
                &featL[swz((it * 16 + lr) * 256 + kt * 32 + lg * 8, lr)]);
        #pragma unroll
        for (int i = 0; i < 4; ++i) {
            int col = (w * 4 + i) * 16 + lr;
            bf[i] = *reinterpret_cast<const short8*>(W1t + (size_t)col * 256 + kt * 32 + lg * 8);
        }
        #pragma unroll
        for (int it = 0; it < ITEMS; ++it)
            #pragma unroll
            for (int i = 0; i < 4; ++i)
                acc[it][i] = __builtin_amdgcn_mfma_f32_16x16x32_bf16(af[it], bf[i], acc[it][i], 0, 0, 0);
    }

    // ---- epilogue: C/D row = lg*4+reg, col = lr. h0 + mean(relu h1 rows 1..10)
    //      feat2 row -> GLOBAL ws (bf16): f2g[item][0:256]=h0, [256:512]=mean h1
    #pragma unroll
    for (int i = 0; i < 4; ++i) {
        const int col = (w * 4 + i) * 16 + lr;
        const float bb = b1[col];
        #pragma unroll
        for (int it = 0; it < ITEMS; ++it) {
            f32x4 a = acc[it][i];
            float r0v = fmaxf(a[0] + bb, 0.f);
            float r1v = fmaxf(a[1] + bb, 0.f);
            float r2v = fmaxf(a[2] + bb, 0.f);
            float r3v = fmaxf(a[3] + bb, 0.f);
            const int rb = lg * 4;
            float p = 0.f;
            p += (rb + 0 >= 1 && rb + 0 <= 10) ? r0v : 0.f;
            p += (rb + 1 >= 1 && rb + 1 <= 10) ? r1v : 0.f;
            p += (rb + 2 >= 1 && rb + 2 <= 10) ? r2v : 0.f;
            p += (rb + 3 >= 1 && rb + 3 <= 10) ? r3v : 0.f;
            p += __shfl_xor(p, 16, 64);
            p += __shfl_xor(p, 32, 64);
            if (lg == 0) {
                ushort* fr = f2g + (size_t)(item0 + it) * 512;
                fr[col]       = f2bf(r0v);
                fr[256 + col] = f2bf(p * (1.f / F1));
            }
        }
    }
}

// ---------------- K2: out = feat2 @ W2 + b2 (128 blocks, M=16) ----------------
__global__ __launch_bounds__(256)
void sage_gemm2(const ushort* __restrict__ f2g, const ushort* __restrict__ W2t,
                const float* __restrict__ b2, float* __restrict__ out)
{
    const int t = threadIdx.x;
    const int w = t >> 6, l = t & 63;
    const int lr = l & 15, lg = l >> 4;
    const int m0 = blockIdx.x * 16;              // 16 items per block

    f32x4 acc[4];
    #pragma unroll
    for (int i = 0; i < 4; ++i) acc[i] = (f32x4){0.f, 0.f, 0.f, 0.f};

    #pragma unroll 2
    for (int kt = 0; kt < 16; ++kt) {
        short8 af = *reinterpret_cast<const short8*>(
            f2g + (size_t)(m0 + lr) * 512 + kt * 32 + lg * 8);
        #pragma unroll
        for (int i = 0; i < 4; ++i) {
            int col = (w * 4 + i) * 16 + lr;
            short8 bv = *reinterpret_cast<const short8*>(
                W2t + (size_t)col * 512 + kt * 32 + lg * 8);
            acc[i] = __builtin_amdgcn_mfma_f32_16x16x32_bf16(af, bv, acc[i], 0, 0, 0);
        }
    }
    #pragma unroll
    for (int i = 0; i < 4; ++i) {
        const int col = (w * 4 + i) * 16 + lr;
        const float bb = b2[col];
        #pragma unroll
        for (int r = 0; r < 4; ++r) {
            const int row = lg * 4 + r;          // 0..15, all valid
            out[(size_t)(m0 + row) * HH + col] = acc[i][r] + bb;
        }
    }
}

extern "C" void kernel_launch(void* const* d_in, const int* in_sizes, int n_in,
                              void* d_out, int out_size, void* d_ws, size_t ws_size,
                              hipStream_t stream) {
    const float* x  = (const float*)d_in[0];
    const float* W1 = (const float*)d_in[1];
    const float* b1 = (const float*)d_in[2];
    const float* W2 = (const float*)d_in[3];
    const float* b2 = (const float*)d_in[4];
    float* out = (float*)d_out;

    ushort* W1t = (ushort*)d_ws;                 // 256*256 bf16 = 128 KB
    ushort* W2t = W1t + 256 * 256;               // 256*512 bf16 = 256 KB
    ushort* f2g = W2t + 256 * 512;               // 2048*512 bf16 = 2 MB

    prep_weights<<<dim3(96), dim3(256), 0, stream>>>(W1, W2, W1t, W2t);
    sage_feat<<<dim3(NB / ITEMS), dim3(THREADS), 0, stream>>>(x, W1t, b1, f2g);
    sage_gemm2<<<dim3(NB / 16), dim3(256), 0, stream>>>(f2g, W2t, b2, out);
}